// Round 7
// baseline (984.187 us; speedup 1.0000x reference)
//
#include <hip/hip_runtime.h>
#include <hip/hip_bf16.h>
#include <cstdint>

#define NB 32
#define NT 2000
#define TP 2048
#define NENC 1024
#define NDEC 1024
#define NATTN 512
#define NHEAD 4
#define NH 2048      // NHEAD*NATTN
#define NC 64
#define NKS 50
#define NKLEN 101
#define NPH 256
#define NPROF 101

typedef __attribute__((ext_vector_type(8))) short bf16x8;
typedef __attribute__((ext_vector_type(4))) float f32x4;
typedef __attribute__((ext_vector_type(8))) unsigned short u16x8;

__device__ __forceinline__ void gload_lds16(const void* g, void* l) {
    __builtin_amdgcn_global_load_lds((__attribute__((address_space(1))) void*)(g),
                                     (__attribute__((address_space(3))) void*)(l), 16, 0, 0);
}

__device__ __forceinline__ unsigned short f2bf(float f) {
    unsigned u = __float_as_uint(f);
    return (unsigned short)((u + 0x7fffu + ((u >> 16) & 1u)) >> 16);
}

__device__ __forceinline__ int prof_of(int t, int len) {
    if (t < NKS) return t;
    if (t < len - NKS) return NKS;
    if (t < len) return NKS + 1 + (t - (len - NKS));
    return NKS;
}

__device__ __forceinline__ float4 f4add3(float4 a, float4 b, float4 c) {
    return make_float4(a.x + b.x + c.x, a.y + b.y + c.y, a.z + b.z + c.z, a.w + b.w + c.w);
}
__device__ __forceinline__ float4 f4fma(float s, float4 a, float4 acc) {
    return make_float4(fmaf(s, a.x, acc.x), fmaf(s, a.y, acc.y),
                       fmaf(s, a.z, acc.z), fmaf(s, a.w, acc.w));
}

// ---------------- f32 -> bf16 conversion (vectorized 8/thread) ----------------
__global__ void k_convert(const float* __restrict__ src, unsigned short* __restrict__ dst, int n8) {
    int stride = gridDim.x * blockDim.x;
    for (int i = blockIdx.x * blockDim.x + threadIdx.x; i < n8; i += stride) {
        const float4* s = (const float4*)(src) + (size_t)i * 2;
        float4 x = s[0], y = s[1];
        u16x8 o;
        o[0] = f2bf(x.x); o[1] = f2bf(x.y); o[2] = f2bf(x.z); o[3] = f2bf(x.w);
        o[4] = f2bf(y.x); o[5] = f2bf(y.y); o[6] = f2bf(y.z); o[7] = f2bf(y.w);
        *((u16x8*)dst + i) = o;
    }
}

// ---------------- prefix sums of Wconv rows: wcum[hc][0..101] ----------------
__global__ void k_wcum(const float* __restrict__ Wconv, float* __restrict__ wcum) {
    int hc = threadIdx.x;  // 256 rows
    float c = 0.f;
    wcum[hc * 102] = 0.f;
    for (int k = 0; k < NKLEN; ++k) {
        c += Wconv[hc * NKLEN + k];
        wcum[hc * 102 + k + 1] = c;
    }
}

// ---------------- WlocT[c][n] = Wloc[n][c] (512 KB, one-shot) ----------------
__global__ void k_wlocT(const float* __restrict__ Wloc, float* __restrict__ wlocT) {
    int c = blockIdx.x;  // 64
    for (int n = threadIdx.x; n < NH; n += 256)
        wlocT[c * NH + n] = Wloc[(size_t)n * NC + c];
}

// ---------------- dec_h[h][b][a] = Wdec[h,a,:].dec[b,:] + bdec ----------------
__global__ void k_dech(const float* __restrict__ dec, const float* __restrict__ Wdec,
                       const float* __restrict__ bdec, float* __restrict__ dech) {
    int h = blockIdx.x >> 5, b = blockIdx.x & 31;
    __shared__ float dl[NDEC];
    int tid = threadIdx.x;
    for (int r = 0; r < 4; ++r) dl[tid + r * 256] = dec[b * NDEC + tid + r * 256];
    __syncthreads();
    for (int a2 = 0; a2 < 2; ++a2) {
        int a = tid + a2 * 256;
        const float4* wr = (const float4*)&Wdec[((size_t)(h * NATTN + a)) * NDEC];
        float acc = 0.f;
        for (int e4 = 0; e4 < NDEC / 4; ++e4) {
            float4 w4 = wr[e4];
            acc += w4.x * dl[e4 * 4] + w4.y * dl[e4 * 4 + 1] + w4.z * dl[e4 * 4 + 2] + w4.w * dl[e4 * 4 + 3];
        }
        dech[(h * NB + b) * NATTN + a] = acc + bdec[h * NATTN + a];
    }
}

// ---- add[b][p][n] = dec_h + benc + bloc + WlocT^T . conv_profile(p) ----------
__global__ void k_addprof(const float* __restrict__ wcum, const float* __restrict__ dech,
                          const float* __restrict__ benc, const float* __restrict__ bloc,
                          const float* __restrict__ wlocT, const int* __restrict__ enc_len,
                          float* __restrict__ addp) {
    int p0 = blockIdx.x * 4, b = blockIdx.y;
    int len = enc_len[b];
    __shared__ float convp[4][256];
    int tid = threadIdx.x;
    float invl = 1.f / (float)len;
#pragma unroll
    for (int pp = 0; pp < 4; ++pp) {
        int p = min(p0 + pp, NPROF - 1);
        int kmin, kmax;
        if (p < NKS)       { kmin = NKS - p; kmax = min(NKLEN, len - p + NKS); }
        else if (p == NKS) { kmin = 0;       kmax = NKLEN; }
        else               { kmin = 0;       kmax = 151 - p; }
        if (kmax < kmin) kmax = kmin;
        convp[pp][tid] = (wcum[tid * 102 + kmax] - wcum[tid * 102 + kmin]) * invl;
    }
    __syncthreads();
    int h0 = tid >> 7, h1 = 2 + h0;
    int n40 = tid, n41 = 256 + tid;   // float4 indices into the 2048-wide n dim
    const float4* dech4 = (const float4*)dech;
    const float4* benc4 = (const float4*)benc;
    const float4* bloc4 = (const float4*)bloc;
    float4 base0 = f4add3(dech4[(h0 * NB + b) * 128 + (tid & 127)], benc4[n40], bloc4[n40]);
    float4 base1 = f4add3(dech4[(h1 * NB + b) * 128 + (tid & 127)], benc4[n41], bloc4[n41]);
    float4 acc[4][2];
#pragma unroll
    for (int pp = 0; pp < 4; ++pp) { acc[pp][0] = base0; acc[pp][1] = base1; }
    const float4* wT4 = (const float4*)wlocT;
#pragma unroll 4
    for (int c = 0; c < NC; ++c) {
        float4 w0 = wT4[c * 512 + n40];
        float4 w1 = wT4[c * 512 + n41];
#pragma unroll
        for (int pp = 0; pp < 4; ++pp) {
            acc[pp][0] = f4fma(convp[pp][h0 * 64 + c], w0, acc[pp][0]);
            acc[pp][1] = f4fma(convp[pp][h1 * 64 + c], w1, acc[pp][1]);
        }
    }
    float4* addp4 = (float4*)addp;
#pragma unroll
    for (int pp = 0; pp < 4; ++pp) {
        int p = p0 + pp;
        if (p < NPROF) {
            addp4[((size_t)(b * NPROF + p)) * 512 + n40] = acc[pp][0];
            addp4[((size_t)(b * NPROF + p)) * 512 + n41] = acc[pp][1];
        }
    }
}

// ---------------- main fused GEMM + tanh + wattn-reduce -> scores -------------
// v2: 256 persistent blocks (1/CU), each = (b, bx), loops over by t-tiles.
// BK=64, dbuf-2 (2 x 64KB), ONE __syncthreads per K-tile (its vmcnt(0)/lgkm(0)
// validates stages issued a full tile earlier -> cheap). Compiler manages all
// lgkm waits for the plain-C++ ds reads. XOR swizzle chunk^=(row&7) on 16B
// chunks: frag reads are 2-way bank aliased (free), gload_lds dest is linear.
__global__ __launch_bounds__(512, 2) void k_gemm(
        const unsigned short* __restrict__ encbf, const unsigned short* __restrict__ wencbf,
        const float* __restrict__ addp, const float* __restrict__ wattn,
        const int* __restrict__ enc_len, float* __restrict__ scores) {
    extern __shared__ char smem[];
    int bid = blockIdx.x;
    int b = (bid & 7) + 8 * ((bid >> 3) & 3);   // b%8 == bid%8 -> all 8 bx of b on one XCD
    int bx = bid >> 5;
    int n0 = bx * 256;
    int len = enc_len[b];
    int tid = threadIdx.x, lane = tid & 63, w = tid >> 6;
    int wr = w >> 2, wc = w & 3;
    int ro = lane & 15, g4 = lane >> 4;

    // staging: wave w owns rows w*32..w*32+31; group g covers rows +g*8..+g*8+7.
    // lane -> row w*32+g*8+(lane>>3), chunk (lane&7); source chunk = chunk^(row&7).
    int lrow = lane >> 3, lch = lane & 7;
    size_t soff = (size_t)(w * 32 + lrow) * NENC + (size_t)((lch ^ lrow) * 8);
    const unsigned short* aBase = encbf + (size_t)b * NT * NENC + soff;   // + t0*NENC + kb + g*8*NENC
    const unsigned short* bBase = wencbf + (size_t)n0 * NENC + soff;
    int wof = w * 4096;

    // read-side addressing (row&7 == ro&7 for both A and B frags)
    int rdAr = (wr * 128 + ro) * 128;
    int rdBr = 32768 + (wc * 64 + ro) * 128;
    int ch0 = ((g4) ^ (ro & 7)) * 16;          // k-half 0 chunk byte
    int ch1 = ((4 + g4) ^ (ro & 7)) * 16;      // k-half 1 chunk byte

    float wat[4];
#pragma unroll
    for (int n = 0; n < 4; ++n) wat[n] = wattn[n0 + wc * 64 + n * 16 + ro];
    int h = n0 >> 9;
    const float* addb0 = addp + (size_t)b * NPROF * NH + n0 + wc * 64 + ro;
    float* sr = scores + ((size_t)(h * NB + b)) * TP;

    auto STA = [&](char* S, const unsigned short* ap) {
#pragma unroll
        for (int g = 0; g < 4; ++g) gload_lds16(ap + (size_t)g * 8 * NENC, S + wof + g * 1024);
    };
    auto STB = [&](char* S, const unsigned short* bp) {
#pragma unroll
        for (int g = 0; g < 4; ++g) gload_lds16(bp + (size_t)g * 8 * NENC, S + 32768 + wof + g * 1024);
    };

#define MFMA_CL(ACOL, BF, N0, N1) \
    __builtin_amdgcn_s_setprio(1); \
    _Pragma("unroll") \
    for (int m = 0; m < 8; ++m) { \
        acc[m][N0] = __builtin_amdgcn_mfma_f32_16x16x32_bf16(ACOL[m], BF[N0 & 1 ? 1 : 0], acc[m][N0], 0, 0, 0); \
        acc[m][N1] = __builtin_amdgcn_mfma_f32_16x16x32_bf16(ACOL[m], BF[N1 & 1 ? 1 : 0] + 0 * BF[0], acc[m][N1], 0, 0, 0); } \
    __builtin_amdgcn_s_setprio(0);

    // prologue: stage by=0 tile 0 into buf0
    STA(smem, aBase);
    STB(smem, bBase);
    __syncthreads();

    for (int by = 0;; ++by) {
        int t0 = by * 256;
        const unsigned short* aBy = aBase + (size_t)t0 * NENC;
        f32x4 acc[8][4] = {};

#pragma unroll 2
        for (int kt = 0; kt < 16; ++kt) {
            const char* R = smem + (kt & 1) * 65536;
            char* S = smem + ((kt & 1) ^ 1) * 65536;
            int kb2 = (kt + 1) * 64;
            bool stg = kt < 15;
            bf16x8 A0[8], A1[8], B0[4], B1[4];
#pragma unroll
            for (int m = 0; m < 8; ++m) A0[m] = *(const bf16x8*)(R + rdAr + m * 2048 + ch0);
#pragma unroll
            for (int n = 0; n < 4; ++n) B0[n] = *(const bf16x8*)(R + rdBr + n * 2048 + ch0);
            if (stg) STA(S, aBy + kb2);
            __builtin_amdgcn_sched_barrier(0);
            __builtin_amdgcn_s_setprio(1);
#pragma unroll
            for (int m = 0; m < 8; ++m) {
                acc[m][0] = __builtin_amdgcn_mfma_f32_16x16x32_bf16(A0[m], B0[0], acc[m][0], 0, 0, 0);
                acc[m][1] = __builtin_amdgcn_mfma_f32_16x16x32_bf16(A0[m], B0[1], acc[m][1], 0, 0, 0);
            }
            __builtin_amdgcn_s_setprio(0);
#pragma unroll
            for (int m = 0; m < 8; ++m) A1[m] = *(const bf16x8*)(R + rdAr + m * 2048 + ch1);
            if (stg) STB(S, bBase + kb2);
            __builtin_amdgcn_sched_barrier(0);
            __builtin_amdgcn_s_setprio(1);
#pragma unroll
            for (int m = 0; m < 8; ++m) {
                acc[m][2] = __builtin_amdgcn_mfma_f32_16x16x32_bf16(A0[m], B0[2], acc[m][2], 0, 0, 0);
                acc[m][3] = __builtin_amdgcn_mfma_f32_16x16x32_bf16(A0[m], B0[3], acc[m][3], 0, 0, 0);
            }
            __builtin_amdgcn_s_setprio(0);
#pragma unroll
            for (int n = 0; n < 4; ++n) B1[n] = *(const bf16x8*)(R + rdBr + n * 2048 + ch1);
            __builtin_amdgcn_s_setprio(1);
#pragma unroll
            for (int m = 0; m < 8; ++m) {
                acc[m][0] = __builtin_amdgcn_mfma_f32_16x16x32_bf16(A1[m], B1[0], acc[m][0], 0, 0, 0);
                acc[m][1] = __builtin_amdgcn_mfma_f32_16x16x32_bf16(A1[m], B1[1], acc[m][1], 0, 0, 0);
            }
#pragma unroll
            for (int m = 0; m < 8; ++m) {
                acc[m][2] = __builtin_amdgcn_mfma_f32_16x16x32_bf16(A1[m], B1[2], acc[m][2], 0, 0, 0);
                acc[m][3] = __builtin_amdgcn_mfma_f32_16x16x32_bf16(A1[m], B1[3], acc[m][3], 0, 0, 0);
            }
            __builtin_amdgcn_s_setprio(0);
            __syncthreads();   // vmcnt(0): own stages (issued ~1 tile ago) retired; barrier: all waves
        }

        bool nxt = (t0 + 256 < len) && (by < 7);
        if (nxt) {  // stage next by's tile 0 into buf0 (free: tile15 used buf1), overlaps epilogue
            STA(smem, aBy + 256 * NENC);
            STB(smem, bBase);
        }

        // epilogue: tanh(acc+add)*wattn, 16-lane reduce over n, atomicAdd to scores
        const float* addb = addb0;
#pragma unroll
        for (int m = 0; m < 8; ++m) {
#pragma unroll
            for (int e = 0; e < 4; ++e) {
                int t = t0 + wr * 128 + m * 16 + g4 * 4 + e;
                int tc = t < NT ? t : NT - 1;
                const float* arow = addb + (size_t)prof_of(tc, len) * NH;
                float s = 0.f;
#pragma unroll
                for (int n = 0; n < 4; ++n) {
                    float v = acc[m][n][e] + arow[n * 16];
                    v = fminf(fmaxf(v, -15.f), 15.f);
                    float e2 = __expf(2.f * v);
                    s += ((e2 - 1.f) / (e2 + 1.f)) * wat[n];
                }
                s += __shfl_xor(s, 1); s += __shfl_xor(s, 2);
                s += __shfl_xor(s, 4); s += __shfl_xor(s, 8);
                if (ro == 0) atomicAdd(&sr[t], s);
            }
        }
        if (!nxt) break;
        __syncthreads();   // validates next by's tile 0
    }
#undef MFMA_CL
}

// ---------------- masked softmax over t per (h,b) -> attn ---------------------
__global__ void k_softmax(const float* __restrict__ scores, const int* __restrict__ enc_len,
                          float* __restrict__ attn) {
    int h = blockIdx.x >> 5, b = blockIdx.x & 31;
    int len = enc_len[b];
    int tid = threadIdx.x;
    const float* row = scores + ((size_t)(h * NB + b)) * TP;
    __shared__ float red[4];
    float m = -1e30f;
    for (int t = tid; t < len; t += 256) m = fmaxf(m, row[t]);
    for (int d = 32; d; d >>= 1) m = fmaxf(m, __shfl_xor(m, d));
    if ((tid & 63) == 0) red[tid >> 6] = m;
    __syncthreads();
    m = fmaxf(fmaxf(red[0], red[1]), fmaxf(red[2], red[3]));
    __syncthreads();
    float z = 0.f;
    for (int t = tid; t < len; t += 256) z += __expf(row[t] - m);
    for (int d = 32; d; d >>= 1) z += __shfl_xor(z, d);
    if ((tid & 63) == 0) red[tid >> 6] = z;
    __syncthreads();
    z = red[0] + red[1] + red[2] + red[3];
    float inv = 1.f / z;
    for (int t = tid; t < NT; t += 256) {
        float av = (t < len) ? __expf(row[t] - m) * inv : 0.f;
        attn[((size_t)(h * NB + b)) * NT + t] = av;
    }
}

// ---------------- attn_weight = mean over heads ------------------------------
__global__ void k_attnw(const float* __restrict__ attn, float* __restrict__ out) {
    int b = blockIdx.y;
    int t = blockIdx.x * 256 + threadIdx.x;
    if (t < NT) {
        float s = 0.f;
        for (int h = 0; h < NHEAD; ++h) s += attn[((size_t)(h * NB + b)) * NT + t];
        out[NB * 1024 + b * NT + t] = 0.25f * s;
    }
}

// ---------------- ctx partials: [ts][h][b][e] --------------------------------
__global__ void k_ctx(const float* __restrict__ enc, const float* __restrict__ attn,
                      const int* __restrict__ enc_len, float* __restrict__ ctxp) {
    int ec = blockIdx.x, ts = blockIdx.y, b = blockIdx.z;
    int tid = threadIdx.x;
    __shared__ float attnL[NHEAD][500];
    int t0 = ts * 500;
    for (int i = tid; i < NHEAD * 500; i += 256) {
        int hh = i / 500, tt = i - hh * 500;
        attnL[hh][tt] = attn[((size_t)(hh * NB + b)) * NT + t0 + tt];
    }
    __syncthreads();
    int len = enc_len[b];
    int t1 = min(t0 + 500, len);
    int e = ec * 256 + tid;
    float a0 = 0.f, a1 = 0.f, a2 = 0.f, a3 = 0.f;
    for (int t = t0; t < t1; ++t) {
        float ev = enc[((size_t)b * NT + t) * NENC + e];
        int tt = t - t0;
        a0 += attnL[0][tt] * ev; a1 += attnL[1][tt] * ev;
        a2 += attnL[2][tt] * ev; a3 += attnL[3][tt] * ev;
    }
    ctxp[(((size_t)ts * NHEAD + 0) * NB + b) * NENC + e] = a0;
    ctxp[(((size_t)ts * NHEAD + 1) * NB + b) * NENC + e] = a1;
    ctxp[(((size_t)ts * NHEAD + 2) * NB + b) * NENC + e] = a2;
    ctxp[(((size_t)ts * NHEAD + 3) * NB + b) * NENC + e] = a3;
}

// ---------------- out[h][b][o] = Wout[h,o,:].ctx + bout ----------------------
__global__ void k_out(const float* __restrict__ ctxp, const float* __restrict__ Wout,
                      const float* __restrict__ bout, float* __restrict__ out) {
    int b = blockIdx.x, h = blockIdx.y;
    int tid = threadIdx.x;
    __shared__ float ctxL[NENC];
    for (int r = 0; r < 4; ++r) {
        int e = tid + r * 256;
        float s = 0.f;
        for (int s4 = 0; s4 < 4; ++s4) s += ctxp[(((size_t)s4 * NHEAD + h) * NB + b) * NENC + e];
        ctxL[e] = s;
    }
    __syncthreads();
    int o = tid;
    float acc = bout[h * NPH + o];
    const float4* wrow = (const float4*)&Wout[((size_t)(h * NPH + o)) * NENC];
    for (int e4 = 0; e4 < NENC / 4; ++e4) {
        float4 w4 = wrow[e4];
        acc += w4.x * ctxL[e4 * 4] + w4.y * ctxL[e4 * 4 + 1] + w4.z * ctxL[e4 * 4 + 2] + w4.w * ctxL[e4 * 4 + 3];
    }
    out[b * 1024 + h * NPH + o] = acc;
}

extern "C" void kernel_launch(void* const* d_in, const int* in_sizes, int n_in,
                              void* d_out, int out_size, void* d_ws, size_t ws_size,
                              hipStream_t stream) {
    const float* enc   = (const float*)d_in[0];
    const int*   elen  = (const int*)d_in[1];
    const float* dec   = (const float*)d_in[2];
    const float* Wenc  = (const float*)d_in[3];
    const float* benc  = (const float*)d_in[4];
    const float* Wdec  = (const float*)d_in[5];
    const float* bdec  = (const float*)d_in[6];
    const float* wattn = (const float*)d_in[7];
    const float* Wconv = (const float*)d_in[8];
    const float* Wloc  = (const float*)d_in[9];
    const float* bloc  = (const float*)d_in[10];
    const float* Wout  = (const float*)d_in[11];
    const float* bout  = (const float*)d_in[12];
    float* out = (float*)d_out;

    char* ws = (char*)d_ws;
    size_t off = 0;
    auto alloc = [&](size_t bytes) { size_t o = off; off += (bytes + 255) & ~(size_t)255; return o; };
    unsigned short* encbf  = (unsigned short*)(ws + alloc((size_t)NB * NT * NENC * 2));
    unsigned short* wencbf = (unsigned short*)(ws + alloc((size_t)NH * NENC * 2));
    float* wcum  = (float*)(ws + alloc((size_t)256 * 102 * 4));
    float* wlocT = (float*)(ws + alloc((size_t)NC * NH * 4));
    float* dech  = (float*)(ws + alloc((size_t)NHEAD * NB * NATTN * 4));
    float* addp  = (float*)(ws + alloc((size_t)NB * NPROF * NH * 4));
    float* scor  = (float*)(ws + alloc((size_t)NHEAD * NB * TP * 4));
    float* attn  = (float*)(ws + alloc((size_t)NHEAD * NB * NT * 4));
    float* ctxp  = (float*)(ws + alloc((size_t)4 * NHEAD * NB * NENC * 4));
    if (off > ws_size) return;  // insufficient workspace: bail (validation will flag it)

    hipFuncSetAttribute((const void*)k_gemm, hipFuncAttributeMaxDynamicSharedMemorySize, 131072);

    k_convert<<<2048, 256, 0, stream>>>(enc, encbf, NB * NT * NENC / 8);
    k_convert<<<64, 256, 0, stream>>>(Wenc, wencbf, NH * NENC / 8);
    k_wcum<<<1, 256, 0, stream>>>(Wconv, wcum);
    k_wlocT<<<64, 256, 0, stream>>>(Wloc, wlocT);
    k_dech<<<NHEAD * NB, 256, 0, stream>>>(dec, Wdec, bdec, dech);
    k_addprof<<<dim3((NPROF + 3) / 4, NB), 256, 0, stream>>>(wcum, dech, benc, bloc, wlocT, elen, addp);
    hipMemsetAsync(scor, 0, (size_t)NHEAD * NB * TP * 4, stream);
    k_gemm<<<256, 512, 131072, stream>>>(encbf, wencbf, addp, wattn, elen, scor);
    k_softmax<<<NHEAD * NB, 256, 0, stream>>>(scor, elen, attn);
    k_attnw<<<dim3(8, NB), 256, 0, stream>>>(attn, out);
    k_ctx<<<dim3(4, 4, NB), 256, 0, stream>>>(enc, attn, elen, ctxp);
    k_out<<<dim3(NB, NHEAD), 256, 0, stream>>>(ctxp, Wout, bout, out);
}